// Round 6
// baseline (238.723 us; speedup 1.0000x reference)
//
#include <hip/hip_runtime.h>
#include <hip/hip_bf16.h>

#define BATCH 128
#define NPTS  2048
#define NDIM  3
#define NPROJ 100
#define NTH   256   // 4 waves per block, each wave = one independent (b,l) pair
#define EPT   32    // elements per thread; 64*32 = 2048 per wave

// ---------------------------------------------------------------------------
// Exact cross-lane xor shuffle on the LDS pipe.
// Masks 1..31 -> ds_swizzle bit-mode (xor within 32-lane groups, exact).
// Mask 63 -> ds_bpermute with precomputed byte address (wave64, per-wave op).
// ---------------------------------------------------------------------------
template<int M>
__device__ __forceinline__ float shx(float v, int a63) {
  const int x = __float_as_int(v);
  int r;
  if constexpr (M == 63) r = __builtin_amdgcn_ds_bpermute(a63, x);
  else                   r = __builtin_amdgcn_ds_swizzle(x, (M << 10) | 0x1F);
  return __int_as_float(r);
}

// Intra-thread reversal CE: within each group of G slots, pair (r, G-1-r).
template<int G>
__device__ __forceinline__ void intra_rev(float v[EPT]) {
#pragma unroll
  for (int g = 0; g < EPT; g += G) {
#pragma unroll
    for (int r = 0; r < G / 2; ++r) {
      const float a = v[g + r], b = v[g + G - 1 - r];
      v[g + r] = fminf(a, b);
      v[g + G - 1 - r] = fmaxf(a, b);
    }
  }
}

// Intra-thread xor CE: pair (s, s|J), min to lower slot.
template<int J>
__device__ __forceinline__ void intra_xor(float v[EPT]) {
#pragma unroll
  for (int s = 0; s < EPT; ++s) {
    if ((s & J) == 0) {
      const float a = v[s], b = v[s | J];
      v[s] = fminf(a, b);
      v[s | J] = fmaxf(a, b);
    }
  }
}

// Cross-lane reversal CE on BOTH arrays (stage K): partner lane^M, partner
// slot 31-s. Bursts of 4 symmetric pairs from EACH array -> 16 ds ops in
// flight per waitcnt, 16 temps max live.
template<int M, int HB>
__device__ __forceinline__ void cross_rev2(float vp[EPT], float vq[EPT],
                                           const int lane, const int a63) {
  const bool up = (lane & HB);
#pragma unroll
  for (int c = 0; c < 4; ++c) {
    float op[8], oq[8];
#pragma unroll
    for (int r = 0; r < 4; ++r) {
      const int s = c * 4 + r;             // 0..15
      op[r]     = shx<M>(vp[31 - s], a63); // partner value for vp slot s
      op[4 + r] = shx<M>(vp[s], a63);      // partner value for vp slot 31-s
      oq[r]     = shx<M>(vq[31 - s], a63);
      oq[4 + r] = shx<M>(vq[s], a63);
    }
    if (up) {
#pragma unroll
      for (int r = 0; r < 4; ++r) {
        const int s = c * 4 + r;
        vp[s]      = fmaxf(vp[s], op[r]);
        vp[31 - s] = fmaxf(vp[31 - s], op[4 + r]);
        vq[s]      = fmaxf(vq[s], oq[r]);
        vq[31 - s] = fmaxf(vq[31 - s], oq[4 + r]);
      }
    } else {
#pragma unroll
      for (int r = 0; r < 4; ++r) {
        const int s = c * 4 + r;
        vp[s]      = fminf(vp[s], op[r]);
        vp[31 - s] = fminf(vp[31 - s], op[4 + r]);
        vq[s]      = fminf(vq[s], oq[r]);
        vq[31 - s] = fminf(vq[31 - s], oq[4 + r]);
      }
    }
  }
}

// Cross-lane xor CE on BOTH arrays at lane-stride D: bursts of 8 slots from
// each array -> 16 ds ops in flight per waitcnt.
template<int D>
__device__ __forceinline__ void cross_xor2(float vp[EPT], float vq[EPT],
                                           const int lane, const int a63) {
  const bool up = (lane & D);
#pragma unroll
  for (int c = 0; c < 4; ++c) {
    float op[8], oq[8];
#pragma unroll
    for (int r = 0; r < 8; ++r) {
      op[r] = shx<D>(vp[c * 8 + r], a63);
      oq[r] = shx<D>(vq[c * 8 + r], a63);
    }
    if (up) {
#pragma unroll
      for (int r = 0; r < 8; ++r) {
        vp[c * 8 + r] = fmaxf(vp[c * 8 + r], op[r]);
        vq[c * 8 + r] = fmaxf(vq[c * 8 + r], oq[r]);
      }
    } else {
#pragma unroll
      for (int r = 0; r < 8; ++r) {
        vp[c * 8 + r] = fminf(vp[c * 8 + r], op[r]);
        vq[c * 8 + r] = fminf(vq[c * 8 + r], oq[r]);
      }
    }
  }
}

#define IR(G)     intra_rev<G>(vp); intra_rev<G>(vq)
#define IX(J)     intra_xor<J>(vp); intra_xor<J>(vq)
#define CRV(M,HB) cross_rev2<M,HB>(vp, vq, lane, a63)
#define CXR(D)    cross_xor2<D>(vp, vq, lane, a63)

// ---------------------------------------------------------------------------
// 256-thread block = 4 waves = 4 independent (b,l) pairs. Per wave: project,
// fixed-direction register bitonic sort (no LDS, no barriers), one partial.
// ---------------------------------------------------------------------------
__global__ __launch_bounds__(NTH) void swd_sort_kernel(
    const float* __restrict__ P, const float* __restrict__ Q,
    const float* __restrict__ proj, float* __restrict__ partial) {
  const int pair = blockIdx.x * 4 + (threadIdx.x >> 6);  // (b,l) index
  const int b = pair / NPROJ;
  const int l = pair - b * NPROJ;
  const int lane = threadIdx.x & 63;
  const int a63 = ((lane ^ 63) << 2);

  const float d0 = proj[b * NDIM * NPROJ + l];
  const float d1 = proj[b * NDIM * NPROJ + NPROJ + l];
  const float d2 = proj[b * NDIM * NPROJ + 2 * NPROJ + l];

  float vp[EPT], vq[EPT];
  const float4* Pb = reinterpret_cast<const float4*>(P + (size_t)b * NPTS * NDIM) + lane * 24;
  const float4* Qb = reinterpret_cast<const float4*>(Q + (size_t)b * NPTS * NDIM) + lane * 24;
#pragma unroll
  for (int c = 0; c < 8; ++c) {  // 3 float4 = 4 points = 4 slots
    const float4 x = Pb[c * 3 + 0], y = Pb[c * 3 + 1], z = Pb[c * 3 + 2];
    vp[c * 4 + 0] = x.x * d0 + x.y * d1 + x.z * d2;
    vp[c * 4 + 1] = x.w * d0 + y.x * d1 + y.y * d2;
    vp[c * 4 + 2] = y.z * d0 + y.w * d1 + z.x * d2;
    vp[c * 4 + 3] = z.y * d0 + z.z * d1 + z.w * d2;
  }
#pragma unroll
  for (int c = 0; c < 8; ++c) {
    const float4 x = Qb[c * 3 + 0], y = Qb[c * 3 + 1], z = Qb[c * 3 + 2];
    vq[c * 4 + 0] = x.x * d0 + x.y * d1 + x.z * d2;
    vq[c * 4 + 1] = x.w * d0 + y.x * d1 + y.y * d2;
    vq[c * 4 + 2] = y.z * d0 + y.w * d1 + z.x * d2;
    vq[c * 4 + 3] = z.y * d0 + z.z * d1 + z.w * d2;
  }

  // ---- fixed-direction bitonic sort of 2048 (layout i = lane*32 + s) ----
  IR(2);
  IR(4);  IX(1);
  IR(8);  IX(2); IX(1);
  IR(16); IX(4); IX(2); IX(1);
  IR(32); IX(8); IX(4); IX(2); IX(1);
  // K=64
  CRV(1, 1);   IX(16); IX(8); IX(4); IX(2); IX(1);
  // K=128
  CRV(3, 2);   CXR(1); IX(16); IX(8); IX(4); IX(2); IX(1);
  // K=256
  CRV(7, 4);   CXR(2); CXR(1); IX(16); IX(8); IX(4); IX(2); IX(1);
  // K=512
  CRV(15, 8);  CXR(4); CXR(2); CXR(1); IX(16); IX(8); IX(4); IX(2); IX(1);
  // K=1024
  CRV(31, 16); CXR(8); CXR(4); CXR(2); CXR(1); IX(16); IX(8); IX(4); IX(2); IX(1);
  // K=2048
  CRV(63, 32); CXR(16); CXR(8); CXR(4); CXR(2); CXR(1); IX(16); IX(8); IX(4); IX(2); IX(1);

  // ---- SSD of sorted arrays, wave-level reduce ----
  float acc = 0.f;
#pragma unroll
  for (int s = 0; s < EPT; ++s) {
    const float d = vp[s] - vq[s];
    acc += d * d;
  }
#pragma unroll
  for (int off = 32; off > 0; off >>= 1) acc += __shfl_down(acc, off, 64);
  if (lane == 0) partial[pair] = acc;
}

// Single block: per-batch reduce over L partials, sqrt, mean over B.
__global__ __launch_bounds__(BATCH) void swd_finalize_kernel(
    const float* __restrict__ partial, float* __restrict__ out) {
  const int b = threadIdx.x;  // 0..127
  float s = 0.f;
  for (int l = 0; l < NPROJ; ++l) s += partial[b * NPROJ + l];
  float swd = sqrtf(s / (float)(NPTS * NPROJ));
  for (int off = 32; off > 0; off >>= 1) swd += __shfl_down(swd, off, 64);
  __shared__ float wsum[BATCH / 64];
  if ((threadIdx.x & 63) == 0) wsum[threadIdx.x >> 6] = swd;
  __syncthreads();
  if (threadIdx.x == 0) out[0] = (wsum[0] + wsum[1]) / (float)BATCH;
}

extern "C" void kernel_launch(void* const* d_in, const int* in_sizes, int n_in,
                              void* d_out, int out_size, void* d_ws, size_t ws_size,
                              hipStream_t stream) {
  const float* P    = (const float*)d_in[0];
  const float* Q    = (const float*)d_in[1];
  const float* proj = (const float*)d_in[2];
  float* out = (float*)d_out;
  float* partial = (float*)d_ws;  // BATCH*NPROJ floats = 51.2 KB

  swd_sort_kernel<<<(BATCH * NPROJ) / 4, NTH, 0, stream>>>(P, Q, proj, partial);
  swd_finalize_kernel<<<1, BATCH, 0, stream>>>(partial, out);
}

// Round 7
// 224.822 us; speedup vs baseline: 1.0618x; 1.0618x over previous
//
#include <hip/hip_runtime.h>
#include <hip/hip_bf16.h>

#define BATCH 128
#define NPTS  2048
#define NDIM  3
#define NPROJ 100
#define NTH   256   // 4 waves per block, each wave = one independent (b,l) pair
#define EPT   32    // elements per thread; 64*32 = 2048 per wave

// ---------------------------------------------------------------------------
// Exact cross-lane xor shuffle. DS pipe is ONE per CU (shared by 4 SIMDs) and
// was the R3-R6 bottleneck, so every mask that has a VALU (DPP) encoding goes
// there; only masks with no DPP equivalent (4, 31, 63) stay on DS.
//   xor1 = quad_perm[1,0,3,2], xor2 = [2,3,0,1], xor3 = [3,2,1,0]
//   xor7 = row_half_mirror, xor15 = row_mirror, xor8 = row_ror:8
// ---------------------------------------------------------------------------
template<int M>
__device__ __forceinline__ float shx(float v, int a63) {
  const int x = __float_as_int(v);
  int r;
  if constexpr (M == 1)       r = __builtin_amdgcn_mov_dpp(x, 0xB1, 0xF, 0xF, true);
  else if constexpr (M == 2)  r = __builtin_amdgcn_mov_dpp(x, 0x4E, 0xF, 0xF, true);
  else if constexpr (M == 3)  r = __builtin_amdgcn_mov_dpp(x, 0x1B, 0xF, 0xF, true);
  else if constexpr (M == 7)  r = __builtin_amdgcn_mov_dpp(x, 0x141, 0xF, 0xF, true);  // row_half_mirror
  else if constexpr (M == 8)  r = __builtin_amdgcn_mov_dpp(x, 0x128, 0xF, 0xF, true);  // row_ror:8
  else if constexpr (M == 15) r = __builtin_amdgcn_mov_dpp(x, 0x140, 0xF, 0xF, true);  // row_mirror
  else if constexpr (M == 63) r = __builtin_amdgcn_ds_bpermute(a63, x);
  else                        r = __builtin_amdgcn_ds_swizzle(x, (M << 10) | 0x1F);    // 4, 16, 31
  return __int_as_float(r);
}

// Unordered pair {v[lane], v[lane^16]} via permlane16_swap (VALU) — order is
// unspecified but min/max consumers don't care. Falls back to ds_swizzle.
__device__ __forceinline__ void pair16(float v, float& x0, float& x1) {
#if __has_builtin(__builtin_amdgcn_permlane16_swap)
  auto r = __builtin_amdgcn_permlane16_swap(__float_as_int(v), __float_as_int(v), false, false);
  x0 = __int_as_float(r[0]);
  x1 = __int_as_float(r[1]);
#else
  x0 = v;
  x1 = shx<16>(v, 0);
#endif
}

// Intra-thread reversal CE: within each group of G slots, pair (r, G-1-r).
template<int G>
__device__ __forceinline__ void intra_rev(float v[EPT]) {
#pragma unroll
  for (int g = 0; g < EPT; g += G) {
#pragma unroll
    for (int r = 0; r < G / 2; ++r) {
      const float a = v[g + r], b = v[g + G - 1 - r];
      v[g + r] = fminf(a, b);
      v[g + G - 1 - r] = fmaxf(a, b);
    }
  }
}

// Intra-thread xor CE: pair (s, s|J), min to lower slot.
template<int J>
__device__ __forceinline__ void intra_xor(float v[EPT]) {
#pragma unroll
  for (int s = 0; s < EPT; ++s) {
    if ((s & J) == 0) {
      const float a = v[s], b = v[s | J];
      v[s] = fminf(a, b);
      v[s | J] = fmaxf(a, b);
    }
  }
}

// Cross-lane reversal CE on BOTH arrays (stage K): partner lane^M, partner
// slot 31-s. Shuffles issued at FULL exec (DPP reads from disabled lanes are
// undefined), then branch for min/max.
template<int M, int HB>
__device__ __forceinline__ void cross_rev2(float vp[EPT], float vq[EPT],
                                           const int lane, const int a63) {
  const bool up = (lane & HB);
#pragma unroll
  for (int c = 0; c < 4; ++c) {
    float op[8], oq[8];
#pragma unroll
    for (int r = 0; r < 4; ++r) {
      const int s = c * 4 + r;             // 0..15
      op[r]     = shx<M>(vp[31 - s], a63); // partner value for vp slot s
      op[4 + r] = shx<M>(vp[s], a63);      // partner value for vp slot 31-s
      oq[r]     = shx<M>(vq[31 - s], a63);
      oq[4 + r] = shx<M>(vq[s], a63);
    }
    if (up) {
#pragma unroll
      for (int r = 0; r < 4; ++r) {
        const int s = c * 4 + r;
        vp[s]      = fmaxf(vp[s], op[r]);
        vp[31 - s] = fmaxf(vp[31 - s], op[4 + r]);
        vq[s]      = fmaxf(vq[s], oq[r]);
        vq[31 - s] = fmaxf(vq[31 - s], oq[4 + r]);
      }
    } else {
#pragma unroll
      for (int r = 0; r < 4; ++r) {
        const int s = c * 4 + r;
        vp[s]      = fminf(vp[s], op[r]);
        vp[31 - s] = fminf(vp[31 - s], op[4 + r]);
        vq[s]      = fminf(vq[s], oq[r]);
        vq[31 - s] = fminf(vq[31 - s], oq[4 + r]);
      }
    }
  }
}

// Cross-lane xor CE on BOTH arrays at lane-stride D. D==16 uses the
// permlane16_swap unordered-pair; other masks use exact shuffles.
template<int D>
__device__ __forceinline__ void cross_xor2(float vp[EPT], float vq[EPT],
                                           const int lane, const int a63) {
  const bool up = (lane & D);
#pragma unroll
  for (int c = 0; c < 4; ++c) {
    float bp[8], op[8], bq[8], oq[8];
#pragma unroll
    for (int r = 0; r < 8; ++r) {
      const int s = c * 8 + r;
      if constexpr (D == 16) {
        pair16(vp[s], bp[r], op[r]);
        pair16(vq[s], bq[r], oq[r]);
      } else {
        bp[r] = vp[s]; op[r] = shx<D>(vp[s], a63);
        bq[r] = vq[s]; oq[r] = shx<D>(vq[s], a63);
      }
    }
    if (up) {
#pragma unroll
      for (int r = 0; r < 8; ++r) {
        vp[c * 8 + r] = fmaxf(bp[r], op[r]);
        vq[c * 8 + r] = fmaxf(bq[r], oq[r]);
      }
    } else {
#pragma unroll
      for (int r = 0; r < 8; ++r) {
        vp[c * 8 + r] = fminf(bp[r], op[r]);
        vq[c * 8 + r] = fminf(bq[r], oq[r]);
      }
    }
  }
}

#define IR(G)     intra_rev<G>(vp); intra_rev<G>(vq)
#define IX(J)     intra_xor<J>(vp); intra_xor<J>(vq)
#define CRV(M,HB) cross_rev2<M,HB>(vp, vq, lane, a63)
#define CXR(D)    cross_xor2<D>(vp, vq, lane, a63)

// ---------------------------------------------------------------------------
// 256-thread block = 4 waves = 4 independent (b,l) pairs. Per wave: project,
// fixed-direction register bitonic sort (no LDS, no barriers), one partial.
// ---------------------------------------------------------------------------
__global__ __launch_bounds__(NTH) void swd_sort_kernel(
    const float* __restrict__ P, const float* __restrict__ Q,
    const float* __restrict__ proj, float* __restrict__ partial) {
  const int pair = blockIdx.x * 4 + (threadIdx.x >> 6);  // (b,l) index
  const int b = pair / NPROJ;
  const int l = pair - b * NPROJ;
  const int lane = threadIdx.x & 63;
  const int a63 = ((lane ^ 63) << 2);

  const float d0 = proj[b * NDIM * NPROJ + l];
  const float d1 = proj[b * NDIM * NPROJ + NPROJ + l];
  const float d2 = proj[b * NDIM * NPROJ + 2 * NPROJ + l];

  float vp[EPT], vq[EPT];
  const float4* Pb = reinterpret_cast<const float4*>(P + (size_t)b * NPTS * NDIM) + lane * 24;
  const float4* Qb = reinterpret_cast<const float4*>(Q + (size_t)b * NPTS * NDIM) + lane * 24;
#pragma unroll
  for (int c = 0; c < 8; ++c) {  // 3 float4 = 4 points = 4 slots
    const float4 x = Pb[c * 3 + 0], y = Pb[c * 3 + 1], z = Pb[c * 3 + 2];
    vp[c * 4 + 0] = x.x * d0 + x.y * d1 + x.z * d2;
    vp[c * 4 + 1] = x.w * d0 + y.x * d1 + y.y * d2;
    vp[c * 4 + 2] = y.z * d0 + y.w * d1 + z.x * d2;
    vp[c * 4 + 3] = z.y * d0 + z.z * d1 + z.w * d2;
  }
#pragma unroll
  for (int c = 0; c < 8; ++c) {
    const float4 x = Qb[c * 3 + 0], y = Qb[c * 3 + 1], z = Qb[c * 3 + 2];
    vq[c * 4 + 0] = x.x * d0 + x.y * d1 + x.z * d2;
    vq[c * 4 + 1] = x.w * d0 + y.x * d1 + y.y * d2;
    vq[c * 4 + 2] = y.z * d0 + y.w * d1 + z.x * d2;
    vq[c * 4 + 3] = z.y * d0 + z.z * d1 + z.w * d2;
  }

  // ---- fixed-direction bitonic sort of 2048 (layout i = lane*32 + s) ----
  IR(2);
  IR(4);  IX(1);
  IR(8);  IX(2); IX(1);
  IR(16); IX(4); IX(2); IX(1);
  IR(32); IX(8); IX(4); IX(2); IX(1);
  // K=64
  CRV(1, 1);   IX(16); IX(8); IX(4); IX(2); IX(1);
  // K=128
  CRV(3, 2);   CXR(1); IX(16); IX(8); IX(4); IX(2); IX(1);
  // K=256
  CRV(7, 4);   CXR(2); CXR(1); IX(16); IX(8); IX(4); IX(2); IX(1);
  // K=512
  CRV(15, 8);  CXR(4); CXR(2); CXR(1); IX(16); IX(8); IX(4); IX(2); IX(1);
  // K=1024
  CRV(31, 16); CXR(8); CXR(4); CXR(2); CXR(1); IX(16); IX(8); IX(4); IX(2); IX(1);
  // K=2048
  CRV(63, 32); CXR(16); CXR(8); CXR(4); CXR(2); CXR(1); IX(16); IX(8); IX(4); IX(2); IX(1);

  // ---- SSD of sorted arrays, wave-level reduce ----
  float acc = 0.f;
#pragma unroll
  for (int s = 0; s < EPT; ++s) {
    const float d = vp[s] - vq[s];
    acc += d * d;
  }
#pragma unroll
  for (int off = 32; off > 0; off >>= 1) acc += __shfl_down(acc, off, 64);
  if (lane == 0) partial[pair] = acc;
}

// Single block: per-batch reduce over L partials, sqrt, mean over B.
__global__ __launch_bounds__(BATCH) void swd_finalize_kernel(
    const float* __restrict__ partial, float* __restrict__ out) {
  const int b = threadIdx.x;  // 0..127
  float s = 0.f;
  for (int l = 0; l < NPROJ; ++l) s += partial[b * NPROJ + l];
  float swd = sqrtf(s / (float)(NPTS * NPROJ));
  for (int off = 32; off > 0; off >>= 1) swd += __shfl_down(swd, off, 64);
  __shared__ float wsum[BATCH / 64];
  if ((threadIdx.x & 63) == 0) wsum[threadIdx.x >> 6] = swd;
  __syncthreads();
  if (threadIdx.x == 0) out[0] = (wsum[0] + wsum[1]) / (float)BATCH;
}

extern "C" void kernel_launch(void* const* d_in, const int* in_sizes, int n_in,
                              void* d_out, int out_size, void* d_ws, size_t ws_size,
                              hipStream_t stream) {
  const float* P    = (const float*)d_in[0];
  const float* Q    = (const float*)d_in[1];
  const float* proj = (const float*)d_in[2];
  float* out = (float*)d_out;
  float* partial = (float*)d_ws;  // BATCH*NPROJ floats = 51.2 KB

  swd_sort_kernel<<<(BATCH * NPROJ) / 4, NTH, 0, stream>>>(P, Q, proj, partial);
  swd_finalize_kernel<<<1, BATCH, 0, stream>>>(partial, out);
}

// Round 8
// 224.459 us; speedup vs baseline: 1.0636x; 1.0016x over previous
//
#include <hip/hip_runtime.h>
#include <hip/hip_bf16.h>

#define BATCH 128
#define NPTS  2048
#define NDIM  3
#define NPROJ 100
#define NTH   256   // 4 waves per block, each wave = one independent (b,l) pair
#define EPT   32    // elements per thread; 64*32 = 2048 per wave

// ---------------------------------------------------------------------------
// Exact cross-lane xor shuffle. DS pipe is ONE per CU (shared by 4 SIMDs),
// so every mask that has a VALU (DPP) encoding goes there; only masks with
// no DPP equivalent (4, 31, 63) stay on DS.
//   xor1 = quad_perm[1,0,3,2], xor2 = [2,3,0,1], xor3 = [3,2,1,0]
//   xor7 = row_half_mirror, xor15 = row_mirror, xor8 = row_ror:8
// ---------------------------------------------------------------------------
template<int M>
__device__ __forceinline__ float shx(float v, int a63) {
  const int x = __float_as_int(v);
  int r;
  if constexpr (M == 1)       r = __builtin_amdgcn_mov_dpp(x, 0xB1, 0xF, 0xF, true);
  else if constexpr (M == 2)  r = __builtin_amdgcn_mov_dpp(x, 0x4E, 0xF, 0xF, true);
  else if constexpr (M == 3)  r = __builtin_amdgcn_mov_dpp(x, 0x1B, 0xF, 0xF, true);
  else if constexpr (M == 7)  r = __builtin_amdgcn_mov_dpp(x, 0x141, 0xF, 0xF, true);  // row_half_mirror
  else if constexpr (M == 8)  r = __builtin_amdgcn_mov_dpp(x, 0x128, 0xF, 0xF, true);  // row_ror:8
  else if constexpr (M == 15) r = __builtin_amdgcn_mov_dpp(x, 0x140, 0xF, 0xF, true);  // row_mirror
  else if constexpr (M == 63) r = __builtin_amdgcn_ds_bpermute(a63, x);
  else                        r = __builtin_amdgcn_ds_swizzle(x, (M << 10) | 0x1F);    // 4, 16, 31
  return __int_as_float(r);
}

// Unordered pair {v[lane], v[lane^16]} via permlane16_swap (VALU) — order is
// unspecified but min/max consumers don't care. Falls back to ds_swizzle.
__device__ __forceinline__ void pair16(float v, float& x0, float& x1) {
#if __has_builtin(__builtin_amdgcn_permlane16_swap)
  auto r = __builtin_amdgcn_permlane16_swap(__float_as_int(v), __float_as_int(v), false, false);
  x0 = __int_as_float(r[0]);
  x1 = __int_as_float(r[1]);
#else
  x0 = v;
  x1 = shx<16>(v, 0);
#endif
}

// Intra-thread reversal CE: within each group of G slots, pair (r, G-1-r).
template<int G>
__device__ __forceinline__ void intra_rev(float v[EPT]) {
#pragma unroll
  for (int g = 0; g < EPT; g += G) {
#pragma unroll
    for (int r = 0; r < G / 2; ++r) {
      const float a = v[g + r], b = v[g + G - 1 - r];
      v[g + r] = fminf(a, b);
      v[g + G - 1 - r] = fmaxf(a, b);
    }
  }
}

// Intra-thread xor CE: pair (s, s|J), min to lower slot.
template<int J>
__device__ __forceinline__ void intra_xor(float v[EPT]) {
#pragma unroll
  for (int s = 0; s < EPT; ++s) {
    if ((s & J) == 0) {
      const float a = v[s], b = v[s | J];
      v[s] = fminf(a, b);
      v[s | J] = fmaxf(a, b);
    }
  }
}

// Cross-lane reversal CE on BOTH arrays (stage K): partner lane^M, partner
// slot 31-s. Shuffles issued at FULL exec (DPP reads from disabled lanes are
// undefined), then branch for min/max.
template<int M, int HB>
__device__ __forceinline__ void cross_rev2(float vp[EPT], float vq[EPT],
                                           const int lane, const int a63) {
  const bool up = (lane & HB);
#pragma unroll
  for (int c = 0; c < 4; ++c) {
    float op[8], oq[8];
#pragma unroll
    for (int r = 0; r < 4; ++r) {
      const int s = c * 4 + r;             // 0..15
      op[r]     = shx<M>(vp[31 - s], a63); // partner value for vp slot s
      op[4 + r] = shx<M>(vp[s], a63);      // partner value for vp slot 31-s
      oq[r]     = shx<M>(vq[31 - s], a63);
      oq[4 + r] = shx<M>(vq[s], a63);
    }
    if (up) {
#pragma unroll
      for (int r = 0; r < 4; ++r) {
        const int s = c * 4 + r;
        vp[s]      = fmaxf(vp[s], op[r]);
        vp[31 - s] = fmaxf(vp[31 - s], op[4 + r]);
        vq[s]      = fmaxf(vq[s], oq[r]);
        vq[31 - s] = fmaxf(vq[31 - s], oq[4 + r]);
      }
    } else {
#pragma unroll
      for (int r = 0; r < 4; ++r) {
        const int s = c * 4 + r;
        vp[s]      = fminf(vp[s], op[r]);
        vp[31 - s] = fminf(vp[31 - s], op[4 + r]);
        vq[s]      = fminf(vq[s], oq[r]);
        vq[31 - s] = fminf(vq[31 - s], oq[4 + r]);
      }
    }
  }
}

// Cross-lane xor CE on BOTH arrays at lane-stride D. D==16 uses the
// permlane16_swap unordered-pair; other masks use exact shuffles.
template<int D>
__device__ __forceinline__ void cross_xor2(float vp[EPT], float vq[EPT],
                                           const int lane, const int a63) {
  const bool up = (lane & D);
#pragma unroll
  for (int c = 0; c < 4; ++c) {
    float bp[8], op[8], bq[8], oq[8];
#pragma unroll
    for (int r = 0; r < 8; ++r) {
      const int s = c * 8 + r;
      if constexpr (D == 16) {
        pair16(vp[s], bp[r], op[r]);
        pair16(vq[s], bq[r], oq[r]);
      } else {
        bp[r] = vp[s]; op[r] = shx<D>(vp[s], a63);
        bq[r] = vq[s]; oq[r] = shx<D>(vq[s], a63);
      }
    }
    if (up) {
#pragma unroll
      for (int r = 0; r < 8; ++r) {
        vp[c * 8 + r] = fmaxf(bp[r], op[r]);
        vq[c * 8 + r] = fmaxf(bq[r], oq[r]);
      }
    } else {
#pragma unroll
      for (int r = 0; r < 8; ++r) {
        vp[c * 8 + r] = fminf(bp[r], op[r]);
        vq[c * 8 + r] = fminf(bq[r], oq[r]);
      }
    }
  }
}

#define IR(G)     intra_rev<G>(vp); intra_rev<G>(vq)
#define IX(J)     intra_xor<J>(vp); intra_xor<J>(vq)
#define CRV(M,HB) cross_rev2<M,HB>(vp, vq, lane, a63)
#define CXR(D)    cross_xor2<D>(vp, vq, lane, a63)

// ---------------------------------------------------------------------------
// 256-thread block = 4 waves = 4 independent (b,l) pairs. Per wave: project,
// fixed-direction register bitonic sort (no LDS, no barriers), one partial.
// __launch_bounds__(256, 2): min 2 waves/EU -> 256-VGPR budget, so vp/vq stay
// in architectural VGPRs instead of being spilled to AGPRs (R7: VGPR_Count=68
// with 64 live floats and zero scratch traffic = accvgpr round-trip on every
// compare-exchange, ~4x VALU inflation).
// ---------------------------------------------------------------------------
__global__ __launch_bounds__(NTH, 2) void swd_sort_kernel(
    const float* __restrict__ P, const float* __restrict__ Q,
    const float* __restrict__ proj, float* __restrict__ partial) {
  const int pair = blockIdx.x * 4 + (threadIdx.x >> 6);  // (b,l) index
  const int b = pair / NPROJ;
  const int l = pair - b * NPROJ;
  const int lane = threadIdx.x & 63;
  const int a63 = ((lane ^ 63) << 2);

  const float d0 = proj[b * NDIM * NPROJ + l];
  const float d1 = proj[b * NDIM * NPROJ + NPROJ + l];
  const float d2 = proj[b * NDIM * NPROJ + 2 * NPROJ + l];

  float vp[EPT], vq[EPT];
  const float4* Pb = reinterpret_cast<const float4*>(P + (size_t)b * NPTS * NDIM) + lane * 24;
  const float4* Qb = reinterpret_cast<const float4*>(Q + (size_t)b * NPTS * NDIM) + lane * 24;
#pragma unroll
  for (int c = 0; c < 8; ++c) {  // 3 float4 = 4 points = 4 slots
    const float4 x = Pb[c * 3 + 0], y = Pb[c * 3 + 1], z = Pb[c * 3 + 2];
    vp[c * 4 + 0] = x.x * d0 + x.y * d1 + x.z * d2;
    vp[c * 4 + 1] = x.w * d0 + y.x * d1 + y.y * d2;
    vp[c * 4 + 2] = y.z * d0 + y.w * d1 + z.x * d2;
    vp[c * 4 + 3] = z.y * d0 + z.z * d1 + z.w * d2;
  }
#pragma unroll
  for (int c = 0; c < 8; ++c) {
    const float4 x = Qb[c * 3 + 0], y = Qb[c * 3 + 1], z = Qb[c * 3 + 2];
    vq[c * 4 + 0] = x.x * d0 + x.y * d1 + x.z * d2;
    vq[c * 4 + 1] = x.w * d0 + y.x * d1 + y.y * d2;
    vq[c * 4 + 2] = y.z * d0 + y.w * d1 + z.x * d2;
    vq[c * 4 + 3] = z.y * d0 + z.z * d1 + z.w * d2;
  }

  // ---- fixed-direction bitonic sort of 2048 (layout i = lane*32 + s) ----
  IR(2);
  IR(4);  IX(1);
  IR(8);  IX(2); IX(1);
  IR(16); IX(4); IX(2); IX(1);
  IR(32); IX(8); IX(4); IX(2); IX(1);
  // K=64
  CRV(1, 1);   IX(16); IX(8); IX(4); IX(2); IX(1);
  // K=128
  CRV(3, 2);   CXR(1); IX(16); IX(8); IX(4); IX(2); IX(1);
  // K=256
  CRV(7, 4);   CXR(2); CXR(1); IX(16); IX(8); IX(4); IX(2); IX(1);
  // K=512
  CRV(15, 8);  CXR(4); CXR(2); CXR(1); IX(16); IX(8); IX(4); IX(2); IX(1);
  // K=1024
  CRV(31, 16); CXR(8); CXR(4); CXR(2); CXR(1); IX(16); IX(8); IX(4); IX(2); IX(1);
  // K=2048
  CRV(63, 32); CXR(16); CXR(8); CXR(4); CXR(2); CXR(1); IX(16); IX(8); IX(4); IX(2); IX(1);

  // ---- SSD of sorted arrays, wave-level reduce ----
  float acc = 0.f;
#pragma unroll
  for (int s = 0; s < EPT; ++s) {
    const float d = vp[s] - vq[s];
    acc += d * d;
  }
#pragma unroll
  for (int off = 32; off > 0; off >>= 1) acc += __shfl_down(acc, off, 64);
  if (lane == 0) partial[pair] = acc;
}

// Single block: per-batch reduce over L partials, sqrt, mean over B.
__global__ __launch_bounds__(BATCH) void swd_finalize_kernel(
    const float* __restrict__ partial, float* __restrict__ out) {
  const int b = threadIdx.x;  // 0..127
  float s = 0.f;
  for (int l = 0; l < NPROJ; ++l) s += partial[b * NPROJ + l];
  float swd = sqrtf(s / (float)(NPTS * NPROJ));
  for (int off = 32; off > 0; off >>= 1) swd += __shfl_down(swd, off, 64);
  __shared__ float wsum[BATCH / 64];
  if ((threadIdx.x & 63) == 0) wsum[threadIdx.x >> 6] = swd;
  __syncthreads();
  if (threadIdx.x == 0) out[0] = (wsum[0] + wsum[1]) / (float)BATCH;
}

extern "C" void kernel_launch(void* const* d_in, const int* in_sizes, int n_in,
                              void* d_out, int out_size, void* d_ws, size_t ws_size,
                              hipStream_t stream) {
  const float* P    = (const float*)d_in[0];
  const float* Q    = (const float*)d_in[1];
  const float* proj = (const float*)d_in[2];
  float* out = (float*)d_out;
  float* partial = (float*)d_ws;  // BATCH*NPROJ floats = 51.2 KB

  swd_sort_kernel<<<(BATCH * NPROJ) / 4, NTH, 0, stream>>>(P, Q, proj, partial);
  swd_finalize_kernel<<<1, BATCH, 0, stream>>>(partial, out);
}

// Round 9
// 216.521 us; speedup vs baseline: 1.1025x; 1.0367x over previous
//
#include <hip/hip_runtime.h>
#include <hip/hip_bf16.h>

#define BATCH 128
#define NPTS  2048
#define NDIM  3
#define NPROJ 100
#define NTH   128   // 2 waves per block: wave 0 sorts P, wave 1 sorts Q
#define EPT   32    // elements per thread; 64*32 = 2048 per wave

// ---------------------------------------------------------------------------
// Exact cross-lane xor shuffle. Masks with a DPP encoding ride the VALU pipe;
// masks 4, 16(fallback), 31 use ds_swizzle; 63 uses ds_bpermute.
//   xor1 = quad_perm[1,0,3,2], xor2 = [2,3,0,1], xor3 = [3,2,1,0]
//   xor7 = row_half_mirror, xor15 = row_mirror, xor8 = row_ror:8
// ---------------------------------------------------------------------------
template<int M>
__device__ __forceinline__ float shx(float v, int a63) {
  const int x = __float_as_int(v);
  int r;
  if constexpr (M == 1)       r = __builtin_amdgcn_mov_dpp(x, 0xB1, 0xF, 0xF, true);
  else if constexpr (M == 2)  r = __builtin_amdgcn_mov_dpp(x, 0x4E, 0xF, 0xF, true);
  else if constexpr (M == 3)  r = __builtin_amdgcn_mov_dpp(x, 0x1B, 0xF, 0xF, true);
  else if constexpr (M == 7)  r = __builtin_amdgcn_mov_dpp(x, 0x141, 0xF, 0xF, true);  // row_half_mirror
  else if constexpr (M == 8)  r = __builtin_amdgcn_mov_dpp(x, 0x128, 0xF, 0xF, true);  // row_ror:8
  else if constexpr (M == 15) r = __builtin_amdgcn_mov_dpp(x, 0x140, 0xF, 0xF, true);  // row_mirror
  else if constexpr (M == 63) r = __builtin_amdgcn_ds_bpermute(a63, x);
  else                        r = __builtin_amdgcn_ds_swizzle(x, (M << 10) | 0x1F);    // 4, 16, 31
  return __int_as_float(r);
}

// Unordered pair {v[lane], v[lane^16]} via permlane16_swap (VALU).
__device__ __forceinline__ void pair16(float v, float& x0, float& x1) {
#if __has_builtin(__builtin_amdgcn_permlane16_swap)
  auto r = __builtin_amdgcn_permlane16_swap(__float_as_int(v), __float_as_int(v), false, false);
  x0 = __int_as_float(r[0]);
  x1 = __int_as_float(r[1]);
#else
  x0 = v;
  x1 = shx<16>(v, 0);
#endif
}

// Intra-thread reversal CE: within each group of G slots, pair (r, G-1-r).
template<int G>
__device__ __forceinline__ void intra_rev(float v[EPT]) {
#pragma unroll
  for (int g = 0; g < EPT; g += G) {
#pragma unroll
    for (int r = 0; r < G / 2; ++r) {
      const float a = v[g + r], b = v[g + G - 1 - r];
      v[g + r] = fminf(a, b);
      v[g + G - 1 - r] = fmaxf(a, b);
    }
  }
}

// Intra-thread xor CE: pair (s, s|J), min to lower slot.
template<int J>
__device__ __forceinline__ void intra_xor(float v[EPT]) {
#pragma unroll
  for (int s = 0; s < EPT; ++s) {
    if ((s & J) == 0) {
      const float a = v[s], b = v[s | J];
      v[s] = fminf(a, b);
      v[s | J] = fmaxf(a, b);
    }
  }
}

// Cross-lane reversal CE (single array): partner lane^M, partner slot 31-s.
// Chunked by symmetric pairs (s, 31-s), 8 pairs per chunk -> 16 temps live.
template<int M, int HB>
__device__ __forceinline__ void cross_rev1(float v[EPT], const int lane, const int a63) {
  const bool up = (lane & HB);
#pragma unroll
  for (int c = 0; c < 2; ++c) {
    float o[16];
#pragma unroll
    for (int r = 0; r < 8; ++r) {
      const int s = c * 8 + r;             // 0..15
      o[r]     = shx<M>(v[31 - s], a63);   // partner value for slot s
      o[8 + r] = shx<M>(v[s], a63);        // partner value for slot 31-s
    }
    if (up) {
#pragma unroll
      for (int r = 0; r < 8; ++r) {
        const int s = c * 8 + r;
        v[s]      = fmaxf(v[s], o[r]);
        v[31 - s] = fmaxf(v[31 - s], o[8 + r]);
      }
    } else {
#pragma unroll
      for (int r = 0; r < 8; ++r) {
        const int s = c * 8 + r;
        v[s]      = fminf(v[s], o[r]);
        v[31 - s] = fminf(v[31 - s], o[8 + r]);
      }
    }
  }
}

// Cross-lane xor CE (single array) at lane-stride D; D==16 uses permlane16_swap.
template<int D>
__device__ __forceinline__ void cross_xor1(float v[EPT], const int lane, const int a63) {
  const bool up = (lane & D);
#pragma unroll
  for (int c = 0; c < 2; ++c) {
    float bv[16], o[16];
#pragma unroll
    for (int r = 0; r < 16; ++r) {
      const int s = c * 16 + r;
      if constexpr (D == 16) {
        pair16(v[s], bv[r], o[r]);
      } else {
        bv[r] = v[s];
        o[r] = shx<D>(v[s], a63);
      }
    }
    if (up) {
#pragma unroll
      for (int r = 0; r < 16; ++r) v[c * 16 + r] = fmaxf(bv[r], o[r]);
    } else {
#pragma unroll
      for (int r = 0; r < 16; ++r) v[c * 16 + r] = fminf(bv[r], o[r]);
    }
  }
}

#define IR(G)     intra_rev<G>(v)
#define IX(J)     intra_xor<J>(v)
#define CRV(M,HB) cross_rev1<M,HB>(v, lane, a63)
#define CXR(D)    cross_xor1<D>(v, lane, a63)

// ---------------------------------------------------------------------------
// One 128-thread block per (b, l) pair. Wave 0 projects+sorts P, wave 1
// projects+sorts Q (fully in-register, in-wave). Join via padded LDS for the
// SSD. Halved per-wave state (no hidden reg pressure), halved code body
// (fits L1I), doubled wave count (latency hiding).
// ---------------------------------------------------------------------------
__global__ __launch_bounds__(NTH) void swd_sort_kernel(
    const float* __restrict__ P, const float* __restrict__ Q,
    const float* __restrict__ proj, float* __restrict__ partial) {
  __shared__ float sj[64 * 33];  // padded row stride 33 -> 2-way-max bank use
  const int pair = blockIdx.x;   // (b,l) index
  const int b = pair / NPROJ;
  const int l = pair - b * NPROJ;
  const int wid  = threadIdx.x >> 6;   // 0: P, 1: Q
  const int lane = threadIdx.x & 63;
  const int a63 = ((lane ^ 63) << 2);

  const float d0 = proj[b * NDIM * NPROJ + l];
  const float d1 = proj[b * NDIM * NPROJ + NPROJ + l];
  const float d2 = proj[b * NDIM * NPROJ + 2 * NPROJ + l];

  const float* __restrict__ src = wid ? Q : P;
  const float4* Sb = reinterpret_cast<const float4*>(src + (size_t)b * NPTS * NDIM) + lane * 24;

  float v[EPT];
#pragma unroll
  for (int c = 0; c < 8; ++c) {  // 3 float4 = 4 points = 4 slots
    const float4 x = Sb[c * 3 + 0], y = Sb[c * 3 + 1], z = Sb[c * 3 + 2];
    v[c * 4 + 0] = x.x * d0 + x.y * d1 + x.z * d2;
    v[c * 4 + 1] = x.w * d0 + y.x * d1 + y.y * d2;
    v[c * 4 + 2] = y.z * d0 + y.w * d1 + z.x * d2;
    v[c * 4 + 3] = z.y * d0 + z.z * d1 + z.w * d2;
  }

  // ---- fixed-direction bitonic sort of 2048 (layout i = lane*32 + s) ----
  IR(2);
  IR(4);  IX(1);
  IR(8);  IX(2); IX(1);
  IR(16); IX(4); IX(2); IX(1);
  IR(32); IX(8); IX(4); IX(2); IX(1);
  // K=64
  CRV(1, 1);   IX(16); IX(8); IX(4); IX(2); IX(1);
  // K=128
  CRV(3, 2);   CXR(1); IX(16); IX(8); IX(4); IX(2); IX(1);
  // K=256
  CRV(7, 4);   CXR(2); CXR(1); IX(16); IX(8); IX(4); IX(2); IX(1);
  // K=512
  CRV(15, 8);  CXR(4); CXR(2); CXR(1); IX(16); IX(8); IX(4); IX(2); IX(1);
  // K=1024
  CRV(31, 16); CXR(8); CXR(4); CXR(2); CXR(1); IX(16); IX(8); IX(4); IX(2); IX(1);
  // K=2048
  CRV(63, 32); CXR(16); CXR(8); CXR(4); CXR(2); CXR(1); IX(16); IX(8); IX(4); IX(2); IX(1);

  // ---- join: wave 1 publishes sorted Q, wave 0 computes SSD ----
  if (wid == 1) {
#pragma unroll
    for (int s = 0; s < EPT; ++s) sj[lane * 33 + s] = v[s];
  }
  __syncthreads();
  if (wid == 0) {
    float acc = 0.f;
#pragma unroll
    for (int s = 0; s < EPT; ++s) {
      const float d = v[s] - sj[lane * 33 + s];
      acc += d * d;
    }
#pragma unroll
    for (int off = 32; off > 0; off >>= 1) acc += __shfl_down(acc, off, 64);
    if (lane == 0) partial[pair] = acc;
  }
}

// Single block: per-batch reduce over L partials, sqrt, mean over B.
__global__ __launch_bounds__(BATCH) void swd_finalize_kernel(
    const float* __restrict__ partial, float* __restrict__ out) {
  const int b = threadIdx.x;  // 0..127
  float s = 0.f;
  for (int l = 0; l < NPROJ; ++l) s += partial[b * NPROJ + l];
  float swd = sqrtf(s / (float)(NPTS * NPROJ));
  for (int off = 32; off > 0; off >>= 1) swd += __shfl_down(swd, off, 64);
  __shared__ float wsum[BATCH / 64];
  if ((threadIdx.x & 63) == 0) wsum[threadIdx.x >> 6] = swd;
  __syncthreads();
  if (threadIdx.x == 0) out[0] = (wsum[0] + wsum[1]) / (float)BATCH;
}

extern "C" void kernel_launch(void* const* d_in, const int* in_sizes, int n_in,
                              void* d_out, int out_size, void* d_ws, size_t ws_size,
                              hipStream_t stream) {
  const float* P    = (const float*)d_in[0];
  const float* Q    = (const float*)d_in[1];
  const float* proj = (const float*)d_in[2];
  float* out = (float*)d_out;
  float* partial = (float*)d_ws;  // BATCH*NPROJ floats = 51.2 KB

  swd_sort_kernel<<<BATCH * NPROJ, NTH, 0, stream>>>(P, Q, proj, partial);
  swd_finalize_kernel<<<1, BATCH, 0, stream>>>(partial, out);
}

// Round 10
// 149.812 us; speedup vs baseline: 1.5935x; 1.4453x over previous
//
#include <hip/hip_runtime.h>
#include <hip/hip_bf16.h>

#define BATCH 128
#define NPTS  2048
#define NDIM  3
#define NPROJ 100
#define NTH   128   // 2 waves per block: wave 0 sorts P, wave 1 sorts Q
#define EPT   32    // elements per thread; 64*32 = 2048 per wave

typedef unsigned int u32;

// Branchless integer min/max: v_min_u32 / v_max_u32, NO canonicalization ops
// (float fminf/fmaxf after opaque shuffles forces the backend to insert
// sNaN-canonicalize instructions per operand — suspected 3x VALU bloat).
__device__ __forceinline__ u32 umn(u32 a, u32 b) { return a < b ? a : b; }
__device__ __forceinline__ u32 umx(u32 a, u32 b) { return a > b ? a : b; }

// Order-preserving float->uint key and inverse (no NaNs in data).
__device__ __forceinline__ u32 f2k(float f) {
  const u32 b = __float_as_uint(f);
  return b ^ ((u32)((int)b >> 31) | 0x80000000u);
}
__device__ __forceinline__ float k2f(u32 k) {
  return __uint_as_float(k ^ (~(u32)((int)k >> 31) | 0x80000000u));
}

// ---------------------------------------------------------------------------
// Exact cross-lane xor shuffle. Masks with a DPP encoding ride the VALU pipe;
// masks 4, 31 use ds_swizzle; 63 uses ds_bpermute.
// ---------------------------------------------------------------------------
template<int M>
__device__ __forceinline__ u32 shx(u32 v, int a63) {
  const int x = (int)v;
  int r;
  if constexpr (M == 1)       r = __builtin_amdgcn_mov_dpp(x, 0xB1, 0xF, 0xF, true);
  else if constexpr (M == 2)  r = __builtin_amdgcn_mov_dpp(x, 0x4E, 0xF, 0xF, true);
  else if constexpr (M == 3)  r = __builtin_amdgcn_mov_dpp(x, 0x1B, 0xF, 0xF, true);
  else if constexpr (M == 7)  r = __builtin_amdgcn_mov_dpp(x, 0x141, 0xF, 0xF, true);  // row_half_mirror
  else if constexpr (M == 8)  r = __builtin_amdgcn_mov_dpp(x, 0x128, 0xF, 0xF, true);  // row_ror:8
  else if constexpr (M == 15) r = __builtin_amdgcn_mov_dpp(x, 0x140, 0xF, 0xF, true);  // row_mirror
  else if constexpr (M == 63) r = __builtin_amdgcn_ds_bpermute(a63, x);
  else                        r = __builtin_amdgcn_ds_swizzle(x, (M << 10) | 0x1F);    // 4, 16, 31
  return (u32)r;
}

// Unordered pair {v[lane], v[lane^16]} via permlane16_swap (VALU).
__device__ __forceinline__ void pair16(u32 v, u32& x0, u32& x1) {
#if __has_builtin(__builtin_amdgcn_permlane16_swap)
  auto r = __builtin_amdgcn_permlane16_swap((int)v, (int)v, false, false);
  x0 = (u32)r[0];
  x1 = (u32)r[1];
#else
  x0 = v;
  x1 = shx<16>(v, 0);
#endif
}

// Intra-thread reversal CE: within each group of G slots, pair (r, G-1-r).
template<int G>
__device__ __forceinline__ void intra_rev(u32 v[EPT]) {
#pragma unroll
  for (int g = 0; g < EPT; g += G) {
#pragma unroll
    for (int r = 0; r < G / 2; ++r) {
      const u32 a = v[g + r], b = v[g + G - 1 - r];
      v[g + r] = umn(a, b);
      v[g + G - 1 - r] = umx(a, b);
    }
  }
}

// Intra-thread xor CE: pair (s, s|J), min to lower slot.
template<int J>
__device__ __forceinline__ void intra_xor(u32 v[EPT]) {
#pragma unroll
  for (int s = 0; s < EPT; ++s) {
    if ((s & J) == 0) {
      const u32 a = v[s], b = v[s | J];
      v[s] = umn(a, b);
      v[s | J] = umx(a, b);
    }
  }
}

// Cross-lane reversal CE: partner lane^M, partner slot 31-s. Shuffles at full
// exec, then exec-masked min/max by lane bit HB.
template<int M, int HB>
__device__ __forceinline__ void cross_rev1(u32 v[EPT], const int lane, const int a63) {
  const bool up = (lane & HB);
#pragma unroll
  for (int c = 0; c < 2; ++c) {
    u32 o[16];
#pragma unroll
    for (int r = 0; r < 8; ++r) {
      const int s = c * 8 + r;             // 0..15
      o[r]     = shx<M>(v[31 - s], a63);   // partner value for slot s
      o[8 + r] = shx<M>(v[s], a63);        // partner value for slot 31-s
    }
    if (up) {
#pragma unroll
      for (int r = 0; r < 8; ++r) {
        const int s = c * 8 + r;
        v[s]      = umx(v[s], o[r]);
        v[31 - s] = umx(v[31 - s], o[8 + r]);
      }
    } else {
#pragma unroll
      for (int r = 0; r < 8; ++r) {
        const int s = c * 8 + r;
        v[s]      = umn(v[s], o[r]);
        v[31 - s] = umn(v[31 - s], o[8 + r]);
      }
    }
  }
}

// Cross-lane xor CE at lane-stride D; D==16 uses permlane16_swap.
template<int D>
__device__ __forceinline__ void cross_xor1(u32 v[EPT], const int lane, const int a63) {
  const bool up = (lane & D);
#pragma unroll
  for (int c = 0; c < 2; ++c) {
    u32 bv[16], o[16];
#pragma unroll
    for (int r = 0; r < 16; ++r) {
      const int s = c * 16 + r;
      if constexpr (D == 16) {
        pair16(v[s], bv[r], o[r]);
      } else {
        bv[r] = v[s];
        o[r] = shx<D>(v[s], a63);
      }
    }
    if (up) {
#pragma unroll
      for (int r = 0; r < 16; ++r) v[c * 16 + r] = umx(bv[r], o[r]);
    } else {
#pragma unroll
      for (int r = 0; r < 16; ++r) v[c * 16 + r] = umn(bv[r], o[r]);
    }
  }
}

#define IR(G)     intra_rev<G>(v)
#define IX(J)     intra_xor<J>(v)
#define CRV(M,HB) cross_rev1<M,HB>(v, lane, a63)
#define CXR(D)    cross_xor1<D>(v, lane, a63)

// ---------------------------------------------------------------------------
// One 128-thread block per (b, l) pair. Wave 0 projects+sorts P, wave 1
// projects+sorts Q as monotone uint keys, fully in-register. Join via padded
// LDS for the SSD.
// ---------------------------------------------------------------------------
__global__ __launch_bounds__(NTH) void swd_sort_kernel(
    const float* __restrict__ P, const float* __restrict__ Q,
    const float* __restrict__ proj, float* __restrict__ partial) {
  __shared__ float sj[64 * 33];  // padded row stride 33
  const int pair = blockIdx.x;   // (b,l) index
  const int b = pair / NPROJ;
  const int l = pair - b * NPROJ;
  const int wid  = threadIdx.x >> 6;   // 0: P, 1: Q
  const int lane = threadIdx.x & 63;
  const int a63 = ((lane ^ 63) << 2);

  const float d0 = proj[b * NDIM * NPROJ + l];
  const float d1 = proj[b * NDIM * NPROJ + NPROJ + l];
  const float d2 = proj[b * NDIM * NPROJ + 2 * NPROJ + l];

  const float* __restrict__ src = wid ? Q : P;
  const float4* Sb = reinterpret_cast<const float4*>(src + (size_t)b * NPTS * NDIM) + lane * 24;

  u32 v[EPT];
#pragma unroll
  for (int c = 0; c < 8; ++c) {  // 3 float4 = 4 points = 4 slots
    const float4 x = Sb[c * 3 + 0], y = Sb[c * 3 + 1], z = Sb[c * 3 + 2];
    v[c * 4 + 0] = f2k(x.x * d0 + x.y * d1 + x.z * d2);
    v[c * 4 + 1] = f2k(x.w * d0 + y.x * d1 + y.y * d2);
    v[c * 4 + 2] = f2k(y.z * d0 + y.w * d1 + z.x * d2);
    v[c * 4 + 3] = f2k(z.y * d0 + z.z * d1 + z.w * d2);
  }

  // ---- fixed-direction bitonic sort of 2048 uint keys (i = lane*32 + s) ----
  IR(2);
  IR(4);  IX(1);
  IR(8);  IX(2); IX(1);
  IR(16); IX(4); IX(2); IX(1);
  IR(32); IX(8); IX(4); IX(2); IX(1);
  // K=64
  CRV(1, 1);   IX(16); IX(8); IX(4); IX(2); IX(1);
  // K=128
  CRV(3, 2);   CXR(1); IX(16); IX(8); IX(4); IX(2); IX(1);
  // K=256
  CRV(7, 4);   CXR(2); CXR(1); IX(16); IX(8); IX(4); IX(2); IX(1);
  // K=512
  CRV(15, 8);  CXR(4); CXR(2); CXR(1); IX(16); IX(8); IX(4); IX(2); IX(1);
  // K=1024
  CRV(31, 16); CXR(8); CXR(4); CXR(2); CXR(1); IX(16); IX(8); IX(4); IX(2); IX(1);
  // K=2048
  CRV(63, 32); CXR(16); CXR(8); CXR(4); CXR(2); CXR(1); IX(16); IX(8); IX(4); IX(2); IX(1);

  // ---- join: wave 1 publishes sorted Q (as float), wave 0 computes SSD ----
  if (wid == 1) {
#pragma unroll
    for (int s = 0; s < EPT; ++s) sj[lane * 33 + s] = k2f(v[s]);
  }
  __syncthreads();
  if (wid == 0) {
    float acc = 0.f;
#pragma unroll
    for (int s = 0; s < EPT; ++s) {
      const float d = k2f(v[s]) - sj[lane * 33 + s];
      acc += d * d;
    }
#pragma unroll
    for (int off = 32; off > 0; off >>= 1) acc += __shfl_down(acc, off, 64);
    if (lane == 0) partial[pair] = acc;
  }
}

// Single block: per-batch reduce over L partials, sqrt, mean over B.
__global__ __launch_bounds__(BATCH) void swd_finalize_kernel(
    const float* __restrict__ partial, float* __restrict__ out) {
  const int b = threadIdx.x;  // 0..127
  float s = 0.f;
  for (int l = 0; l < NPROJ; ++l) s += partial[b * NPROJ + l];
  float swd = sqrtf(s / (float)(NPTS * NPROJ));
  for (int off = 32; off > 0; off >>= 1) swd += __shfl_down(swd, off, 64);
  __shared__ float wsum[BATCH / 64];
  if ((threadIdx.x & 63) == 0) wsum[threadIdx.x >> 6] = swd;
  __syncthreads();
  if (threadIdx.x == 0) out[0] = (wsum[0] + wsum[1]) / (float)BATCH;
}

extern "C" void kernel_launch(void* const* d_in, const int* in_sizes, int n_in,
                              void* d_out, int out_size, void* d_ws, size_t ws_size,
                              hipStream_t stream) {
  const float* P    = (const float*)d_in[0];
  const float* Q    = (const float*)d_in[1];
  const float* proj = (const float*)d_in[2];
  float* out = (float*)d_out;
  float* partial = (float*)d_ws;  // BATCH*NPROJ floats = 51.2 KB

  swd_sort_kernel<<<BATCH * NPROJ, NTH, 0, stream>>>(P, Q, proj, partial);
  swd_finalize_kernel<<<1, BATCH, 0, stream>>>(partial, out);
}

// Round 11
// 147.729 us; speedup vs baseline: 1.6160x; 1.0141x over previous
//
#include <hip/hip_runtime.h>
#include <hip/hip_bf16.h>

#define BATCH 128
#define NPTS  2048
#define NDIM  3
#define NPROJ 100
#define NTH   128   // 2 waves per block: wave 0 sorts P, wave 1 sorts Q
#define EPT   32    // elements per thread; 64*32 = 2048 per wave

typedef unsigned int u32;

// Branchless integer min/max: v_min_u32 / v_max_u32 (no canonicalization).
__device__ __forceinline__ u32 umn(u32 a, u32 b) { return a < b ? a : b; }
__device__ __forceinline__ u32 umx(u32 a, u32 b) { return a > b ? a : b; }

// Order-preserving float->uint key and inverse (no NaNs in data).
__device__ __forceinline__ u32 f2k(float f) {
  const u32 b = __float_as_uint(f);
  return b ^ ((u32)((int)b >> 31) | 0x80000000u);
}
__device__ __forceinline__ float k2f(u32 k) {
  return __uint_as_float(k ^ (~(u32)((int)k >> 31) | 0x80000000u));
}

// ---------------------------------------------------------------------------
// Exact cross-lane xor shuffle — ALL on the DS pipe. The kernel is VALU-issue
// bound (R10: VALUBusy ~100%) while the DS pipe runs at ~10% of its per-CU
// budget, so shuffles must NOT consume VALU slots (DPP/permlane do).
// Masks 1..31: ds_swizzle bit-mode (xor within 32-lane halves — exact).
// Mask 63: ds_bpermute with precomputed byte address (full wave64).
// ---------------------------------------------------------------------------
template<int M>
__device__ __forceinline__ u32 shx(u32 v, int a63) {
  const int x = (int)v;
  int r;
  if constexpr (M == 63) r = __builtin_amdgcn_ds_bpermute(a63, x);
  else                   r = __builtin_amdgcn_ds_swizzle(x, (M << 10) | 0x1F);
  return (u32)r;
}

// Intra-thread reversal CE: within each group of G slots, pair (r, G-1-r).
template<int G>
__device__ __forceinline__ void intra_rev(u32 v[EPT]) {
#pragma unroll
  for (int g = 0; g < EPT; g += G) {
#pragma unroll
    for (int r = 0; r < G / 2; ++r) {
      const u32 a = v[g + r], b = v[g + G - 1 - r];
      v[g + r] = umn(a, b);
      v[g + G - 1 - r] = umx(a, b);
    }
  }
}

// Intra-thread xor CE: pair (s, s|J), min to lower slot.
template<int J>
__device__ __forceinline__ void intra_xor(u32 v[EPT]) {
#pragma unroll
  for (int s = 0; s < EPT; ++s) {
    if ((s & J) == 0) {
      const u32 a = v[s], b = v[s | J];
      v[s] = umn(a, b);
      v[s | J] = umx(a, b);
    }
  }
}

// Cross-lane reversal CE: partner lane^M, partner slot 31-s. Shuffles batched
// 16 deep on the DS pipe, then exec-masked min/max (divergent both-branch =
// 2 VALU/elem, the cheapest select-free form).
template<int M, int HB>
__device__ __forceinline__ void cross_rev1(u32 v[EPT], const int lane, const int a63) {
  const bool up = (lane & HB);
#pragma unroll
  for (int c = 0; c < 2; ++c) {
    u32 o[16];
#pragma unroll
    for (int r = 0; r < 8; ++r) {
      const int s = c * 8 + r;             // 0..15
      o[r]     = shx<M>(v[31 - s], a63);   // partner value for slot s
      o[8 + r] = shx<M>(v[s], a63);        // partner value for slot 31-s
    }
    if (up) {
#pragma unroll
      for (int r = 0; r < 8; ++r) {
        const int s = c * 8 + r;
        v[s]      = umx(v[s], o[r]);
        v[31 - s] = umx(v[31 - s], o[8 + r]);
      }
    } else {
#pragma unroll
      for (int r = 0; r < 8; ++r) {
        const int s = c * 8 + r;
        v[s]      = umn(v[s], o[r]);
        v[31 - s] = umn(v[31 - s], o[8 + r]);
      }
    }
  }
}

// Cross-lane xor CE at lane-stride D.
template<int D>
__device__ __forceinline__ void cross_xor1(u32 v[EPT], const int lane, const int a63) {
  const bool up = (lane & D);
#pragma unroll
  for (int c = 0; c < 2; ++c) {
    u32 o[16];
#pragma unroll
    for (int r = 0; r < 16; ++r) o[r] = shx<D>(v[c * 16 + r], a63);
    if (up) {
#pragma unroll
      for (int r = 0; r < 16; ++r) v[c * 16 + r] = umx(v[c * 16 + r], o[r]);
    } else {
#pragma unroll
      for (int r = 0; r < 16; ++r) v[c * 16 + r] = umn(v[c * 16 + r], o[r]);
    }
  }
}

#define IR(G)     intra_rev<G>(v)
#define IX(J)     intra_xor<J>(v)
#define CRV(M,HB) cross_rev1<M,HB>(v, lane, a63)
#define CXR(D)    cross_xor1<D>(v, lane, a63)

// ---------------------------------------------------------------------------
// One 128-thread block per (b, l) pair. Wave 0 projects+sorts P, wave 1
// projects+sorts Q as monotone uint keys, fully in-register. Join via padded
// LDS for the SSD.
// ---------------------------------------------------------------------------
__global__ __launch_bounds__(NTH) void swd_sort_kernel(
    const float* __restrict__ P, const float* __restrict__ Q,
    const float* __restrict__ proj, float* __restrict__ partial) {
  __shared__ float sj[64 * 33];  // padded row stride 33
  const int pair = blockIdx.x;   // (b,l) index
  const int b = pair / NPROJ;
  const int l = pair - b * NPROJ;
  const int wid  = threadIdx.x >> 6;   // 0: P, 1: Q
  const int lane = threadIdx.x & 63;
  const int a63 = ((lane ^ 63) << 2);

  const float d0 = proj[b * NDIM * NPROJ + l];
  const float d1 = proj[b * NDIM * NPROJ + NPROJ + l];
  const float d2 = proj[b * NDIM * NPROJ + 2 * NPROJ + l];

  const float* __restrict__ src = wid ? Q : P;
  const float4* Sb = reinterpret_cast<const float4*>(src + (size_t)b * NPTS * NDIM) + lane * 24;

  u32 v[EPT];
#pragma unroll
  for (int c = 0; c < 8; ++c) {  // 3 float4 = 4 points = 4 slots
    const float4 x = Sb[c * 3 + 0], y = Sb[c * 3 + 1], z = Sb[c * 3 + 2];
    v[c * 4 + 0] = f2k(x.x * d0 + x.y * d1 + x.z * d2);
    v[c * 4 + 1] = f2k(x.w * d0 + y.x * d1 + y.y * d2);
    v[c * 4 + 2] = f2k(y.z * d0 + y.w * d1 + z.x * d2);
    v[c * 4 + 3] = f2k(z.y * d0 + z.z * d1 + z.w * d2);
  }

  // ---- fixed-direction bitonic sort of 2048 uint keys (i = lane*32 + s) ----
  IR(2);
  IR(4);  IX(1);
  IR(8);  IX(2); IX(1);
  IR(16); IX(4); IX(2); IX(1);
  IR(32); IX(8); IX(4); IX(2); IX(1);
  // K=64
  CRV(1, 1);   IX(16); IX(8); IX(4); IX(2); IX(1);
  // K=128
  CRV(3, 2);   CXR(1); IX(16); IX(8); IX(4); IX(2); IX(1);
  // K=256
  CRV(7, 4);   CXR(2); CXR(1); IX(16); IX(8); IX(4); IX(2); IX(1);
  // K=512
  CRV(15, 8);  CXR(4); CXR(2); CXR(1); IX(16); IX(8); IX(4); IX(2); IX(1);
  // K=1024
  CRV(31, 16); CXR(8); CXR(4); CXR(2); CXR(1); IX(16); IX(8); IX(4); IX(2); IX(1);
  // K=2048
  CRV(63, 32); CXR(16); CXR(8); CXR(4); CXR(2); CXR(1); IX(16); IX(8); IX(4); IX(2); IX(1);

  // ---- join: wave 1 publishes sorted Q (as float), wave 0 computes SSD ----
  if (wid == 1) {
#pragma unroll
    for (int s = 0; s < EPT; ++s) sj[lane * 33 + s] = k2f(v[s]);
  }
  __syncthreads();
  if (wid == 0) {
    float acc = 0.f;
#pragma unroll
    for (int s = 0; s < EPT; ++s) {
      const float d = k2f(v[s]) - sj[lane * 33 + s];
      acc += d * d;
    }
#pragma unroll
    for (int off = 32; off > 0; off >>= 1) acc += __shfl_down(acc, off, 64);
    if (lane == 0) partial[pair] = acc;
  }
}

// Single block: per-batch reduce over L partials, sqrt, mean over B.
__global__ __launch_bounds__(BATCH) void swd_finalize_kernel(
    const float* __restrict__ partial, float* __restrict__ out) {
  const int b = threadIdx.x;  // 0..127
  float s = 0.f;
  for (int l = 0; l < NPROJ; ++l) s += partial[b * NPROJ + l];
  float swd = sqrtf(s / (float)(NPTS * NPROJ));
  for (int off = 32; off > 0; off >>= 1) swd += __shfl_down(swd, off, 64);
  __shared__ float wsum[BATCH / 64];
  if ((threadIdx.x & 63) == 0) wsum[threadIdx.x >> 6] = swd;
  __syncthreads();
  if (threadIdx.x == 0) out[0] = (wsum[0] + wsum[1]) / (float)BATCH;
}

extern "C" void kernel_launch(void* const* d_in, const int* in_sizes, int n_in,
                              void* d_out, int out_size, void* d_ws, size_t ws_size,
                              hipStream_t stream) {
  const float* P    = (const float*)d_in[0];
  const float* Q    = (const float*)d_in[1];
  const float* proj = (const float*)d_in[2];
  float* out = (float*)d_out;
  float* partial = (float*)d_ws;  // BATCH*NPROJ floats = 51.2 KB

  swd_sort_kernel<<<BATCH * NPROJ, NTH, 0, stream>>>(P, Q, proj, partial);
  swd_finalize_kernel<<<1, BATCH, 0, stream>>>(partial, out);
}